// Round 7
// baseline (584.317 us; speedup 1.0000x reference)
//
#include <hip/hip_runtime.h>
#include <hip/hip_bf16.h>
#include <math.h>

#define BB 16
#define H1 14
#define W1 254
#define HPH 19
#define HPW2 264    // padded NHWC width (cols 0..263; data at 2..255)
#define NCAP 28448
#define FLATSZ 227584   // 64*14*254

typedef __attribute__((ext_vector_type(8))) short bf16x8;
typedef __attribute__((ext_vector_type(4))) float f32x4;
typedef __attribute__((ext_vector_type(2))) __fp16 f16x2;   // matches cvt_pkrtz return type
typedef __attribute__((ext_vector_type(8))) _Float16 h8;    // MFMA f16 A/B fragment (4 VGPRs)
typedef __attribute__((ext_vector_type(4))) uint uint4v;

__device__ __forceinline__ ushort f2bf(float f) {
  __hip_bfloat16 h = __float2bfloat16(f);
  return *(ushort*)&h;
}

__device__ __forceinline__ h8 h8zero() {
  h8 x;
#pragma unroll
  for (int z = 0; z < 8; z++) x[z] = (_Float16)0.f;
  return x;
}

// ---------- weight prep: wb[co][tap*64+ci] bf16, w3t[c][co] fp32 ----------
__global__ __launch_bounds__(256) void prep_w(const float* __restrict__ w2, const float* __restrict__ w3,
                                              ushort* __restrict__ wb, float* __restrict__ w3t) {
  int idx = blockIdx.x * 256 + threadIdx.x;
  if (idx < 147456) {
    int co = idx / 2304; int rem = idx - co * 2304;
    int tap = rem >> 6; int ci = rem & 63;
    wb[idx] = f2bf(w2[(co * 64 + ci) * 36 + tap]);
  }
  if (idx < 8192) {
    int co = idx & 63; int c = idx >> 6;
    w3t[idx] = w3[co * 128 + c];
  }
}

// ---------- ec_w fp32 -> fp16 (RTZ pack), order-preserving [n][e][o][i] ----------
__global__ __launch_bounds__(256) void cvt_ec(const float* __restrict__ ecw, uint* __restrict__ ech) {
  size_t i = (size_t)blockIdx.x * 256 + threadIdx.x;   // one thread per 8 floats; 3641344 total
  const float4* s = (const float4*)ecw + i * 2;
  float4 a = s[0], b = s[1];
  uint4v pk;
  { f16x2 h = __builtin_amdgcn_cvt_pkrtz(a.x, a.y); pk.x = *(uint*)&h; }
  { f16x2 h = __builtin_amdgcn_cvt_pkrtz(a.z, a.w); pk.y = *(uint*)&h; }
  { f16x2 h = __builtin_amdgcn_cvt_pkrtz(b.x, b.y); pk.z = *(uint*)&h; }
  { f16x2 h = __builtin_amdgcn_cvt_pkrtz(b.z, b.w); pk.w = *(uint*)&h; }
  *((uint4v*)ech + i) = pk;
}

// ---------- u fp32 [b][n][8] -> fp16 [n][b][8] (MFMA A-fragment order) ----------
__global__ __launch_bounds__(256) void cvt_u(const float* __restrict__ u, _Float16* __restrict__ uh) {
  const int idx = blockIdx.x * 256 + threadIdx.x;   // 455168 = NCAP*16 exactly (1778 blocks)
  const int n = idx >> 4, b = idx & 15;
  const float4* s = (const float4*)(u + ((size_t)b * NCAP + n) * 8);
  float4 xa = s[0], xb = s[1];
  h8 o;
  o[0] = (_Float16)xa.x; o[1] = (_Float16)xa.y; o[2] = (_Float16)xa.z; o[3] = (_Float16)xa.w;
  o[4] = (_Float16)xb.x; o[5] = (_Float16)xb.y; o[6] = (_Float16)xb.z; o[7] = (_Float16)xb.w;
  *(h8*)(uh + (size_t)idx * 8) = o;
}

// ---------- conv1: 1->64, 6x6, stride 2 -> compact fp32 hc[b][c][14][254] ----------
__global__ __launch_bounds__(256) void conv1_k(const float* __restrict__ x, const float* __restrict__ w1,
                                               const float* __restrict__ b1, float* __restrict__ hc) {
  const int i = blockIdx.x, b = blockIdx.y;
  __shared__ float xs[6 * 512];
  __shared__ float wsh[2304];
  __shared__ float bsh[64];
  const int t = threadIdx.x;
  for (int idx = t; idx < 6 * 512; idx += 256) {
    int r = idx >> 9, c = idx & 511;
    xs[idx] = x[((size_t)b * 32 + 2 * i + r) * 512 + c];
  }
  for (int idx = t; idx < 2304; idx += 256) wsh[idx] = w1[idx];
  if (t < 64) bsh[t] = b1[t];
  __syncthreads();
  if (t < 254) {
    for (int c = 0; c < 64; c++) {
      float acc = bsh[c];
#pragma unroll
      for (int p = 0; p < 6; p++)
#pragma unroll
        for (int q = 0; q < 6; q++)
          acc = fmaf(xs[p * 512 + 2 * t + q], wsh[c * 36 + p * 6 + q], acc);
      acc = fmaxf(acc, 0.f);
      hc[(((size_t)b * 64 + c) * H1 + i) * W1 + t] = acc;
    }
  }
}

// ---------- transpose hc (NCHW fp32) -> hpc (padded NHWC bf16) ----------
__global__ __launch_bounds__(256) void nhwc_k(const float* __restrict__ hc, ushort* __restrict__ hpc) {
  const int ct = blockIdx.x, i = blockIdx.y, b = blockIdx.z;
  const int c0 = ct * 64;
  __shared__ float ls[64 * 65];
  const int t = threadIdx.x;
  for (int idx = t; idx < 4096; idx += 256) {
    int ci = idx >> 6, cc = idx & 63;
    int c = c0 + cc;
    ls[ci * 65 + cc] = (c < W1) ? hc[(((size_t)b * 64 + ci) * H1 + i) * W1 + c] : 0.f;
  }
  __syncthreads();
  uint* outp = (uint*)hpc;
  for (int idx = t; idx < 2048; idx += 256) {
    int cc = idx >> 5, ci2 = idx & 31;
    int c = c0 + cc;
    if (c < W1) {
      float f0 = ls[(2 * ci2) * 65 + cc];
      float f1 = ls[(2 * ci2 + 1) * 65 + cc];
      uint pk = (uint)f2bf(f0) | ((uint)f2bf(f1) << 16);
      outp[(((size_t)b * HPH + 2 + i) * HPW2 + 2 + c) * 32 + ci2] = pk;
    }
  }
}

// ---------- conv2 implicit-GEMM bf16 MFMA (per-tap LDS double-buffer pipeline) ----------
__device__ __forceinline__ void stage_b(const ushort* __restrict__ wb, ushort* __restrict__ bbuf,
                                        int tap, int w, int l) {
#pragma unroll
  for (int r = 0; r < 2; r++) {
    int v = r * 256 + w * 64 + l;
    int co = v >> 3, s = v & 7;
    int g = s ^ (co & 7);                       // XOR swizzle: slot s holds k-group g
    const ushort* gp = wb + co * 2304 + tap * 64 + g * 8;
    ushort* lp = bbuf + (size_t)(r * 256 + w * 64) * 8;   // wave-uniform base; lane scatters +l*16B
    __builtin_amdgcn_global_load_lds((const uint*)gp, (uint*)lp, 16, 0, 0);
  }
}

__global__ __launch_bounds__(256, 1) void conv2_mfma(const ushort* __restrict__ hpc,
                                                     const ushort* __restrict__ wb,
                                                     const float* __restrict__ b2, float* __restrict__ y) {
  const int b = blockIdx.z, i = blockIdx.y, j0 = blockIdx.x * 128;
  const int t = threadIdx.x;
  const int w = t >> 6, l = t & 63;
  const int lr = l & 15, quad = l >> 4;

  __shared__ ushort bls[2][4096];   // [buf][co*64 + slot*8] bf16, swizzled

  f32x4 acc[2][4];
#pragma unroll
  for (int mt = 0; mt < 2; mt++)
#pragma unroll
    for (int nt = 0; nt < 4; nt++) acc[mt][nt] = (f32x4){0.f, 0.f, 0.f, 0.f};

  const ushort* abase = hpc + (((size_t)b * HPH + i) * HPW2 + (j0 + w * 32 + lr)) * 64 + quad * 8;

  bf16x8 a0[2][2], a1[2][2];   // [ch][mt] for current / next tap

#define ALOAD(dst, tap)                                                        \
  {                                                                            \
    const int p_ = (tap) / 6, q_ = (tap) % 6;                                  \
    const ushort* ap_ = abase + ((size_t)p_ * HPW2 + q_) * 64;                 \
    dst[0][0] = *(const bf16x8*)(ap_);                                         \
    dst[0][1] = *(const bf16x8*)(ap_ + 1024);                                  \
    dst[1][0] = *(const bf16x8*)(ap_ + 32);                                    \
    dst[1][1] = *(const bf16x8*)(ap_ + 32 + 1024);                             \
  }

#define COMPUTE(a, bp)                                                         \
  {                                                                            \
    _Pragma("unroll")                                                          \
    for (int ch = 0; ch < 2; ch++) {                                           \
      const int g2 = ch * 4 + quad;                                            \
      _Pragma("unroll")                                                        \
      for (int nt = 0; nt < 4; nt++) {                                         \
        const int co = nt * 16 + lr;                                           \
        bf16x8 bf = *(const bf16x8*)((bp) + co * 64 + ((g2 ^ (co & 7)) * 8));  \
        acc[0][nt] = __builtin_amdgcn_mfma_f32_16x16x32_bf16(a[ch][0], bf, acc[0][nt], 0, 0, 0); \
        acc[1][nt] = __builtin_amdgcn_mfma_f32_16x16x32_bf16(a[ch][1], bf, acc[1][nt], 0, 0, 0); \
      }                                                                        \
    }                                                                          \
  }

  stage_b(wb, &bls[0][0], 0, w, l);
  __syncthreads();                 // B(0) resident
  ALOAD(a0, 0);

  for (int tp = 0; tp < 36; tp += 2) {
    stage_b(wb, &bls[1][0], tp + 1, w, l);
    ALOAD(a1, tp + 1);
    COMPUTE(a0, &bls[0][0]);
    __syncthreads();
    if (tp + 2 < 36) {
      stage_b(wb, &bls[0][0], tp + 2, w, l);
      ALOAD(a0, tp + 2);
    }
    COMPUTE(a1, &bls[1][0]);
    __syncthreads();
  }

#pragma unroll
  for (int nt = 0; nt < 4; nt++) {
    const int co = nt * 16 + lr;
    const float bias = b2[co];
    float* yrow = y + (((size_t)b * 64 + co) * H1 + i) * W1;
#pragma unroll
    for (int mt = 0; mt < 2; mt++) {
      const int jb = j0 + w * 32 + mt * 16 + quad * 4;
#pragma unroll
      for (int r = 0; r < 4; r++) {
        int j = jb + r;
        if (j < W1) yrow[j] = fmaxf(acc[mt][nt][r] + bias, 0.f);
      }
    }
  }
#undef ALOAD
#undef COMPUTE
}

// ---------- conv3: 1x1, 128->64, over concat(hc, y); NO relu ----------
__global__ __launch_bounds__(256) void conv3_k(const float* __restrict__ hc, const float* __restrict__ y,
                                               const float* __restrict__ w3t, const float* __restrict__ b3,
                                               float* __restrict__ out3) {
  const int b = blockIdx.z, i = blockIdx.y, j0 = blockIdx.x * 64;
  __shared__ float cs[32][64];
  __shared__ float wsh[32][64];
  const int t = threadIdx.x;
  const int cog = t >> 4, jg = t & 15;
  float acc[4][4];
#pragma unroll
  for (int a = 0; a < 4; a++)
#pragma unroll
    for (int j = 0; j < 4; j++) acc[a][j] = 0.f;

  for (int ch = 0; ch < 4; ch++) {
    __syncthreads();
    for (int idx = t; idx < 2048; idx += 256) {
      int cl = idx >> 6; int j = j0 + (idx & 63);
      int c = ch * 32 + cl;
      float v = 0.f;
      if (j < W1) {
        if (c < 64) v = hc[(((size_t)b * 64 + c) * H1 + i) * W1 + j];
        else        v = y[(((size_t)b * 64 + (c - 64)) * H1 + i) * W1 + j];
      }
      cs[cl][idx & 63] = v;
    }
    for (int idx = t; idx < 2048; idx += 256)
      wsh[idx >> 6][idx & 63] = w3t[(ch * 32 + (idx >> 6)) * 64 + (idx & 63)];
    __syncthreads();
#pragma unroll
    for (int c = 0; c < 32; c++) {
      float4 xv = *(const float4*)&cs[c][jg * 4];
      float4 wv = *(const float4*)&wsh[c][cog * 4];
#pragma unroll
      for (int jj = 0; jj < 4; jj++) {
        float xx = (&xv.x)[jj];
        acc[0][jj] = fmaf(wv.x, xx, acc[0][jj]);
        acc[1][jj] = fmaf(wv.y, xx, acc[1][jj]);
        acc[2][jj] = fmaf(wv.z, xx, acc[2][jj]);
        acc[3][jj] = fmaf(wv.w, xx, acc[3][jj]);
      }
    }
  }
#pragma unroll
  for (int a = 0; a < 4; a++) {
    int co = cog * 4 + a;
    float bias = b3[co];
#pragma unroll
    for (int jj = 0; jj < 4; jj++) {
      int j = j0 + jg * 4 + jj;
      if (j < W1) out3[(((size_t)b * 64 + co) * H1 + i) * W1 + j] = acc[a][jj] + bias;
    }
  }
}

// ---------- pc: per-capsule 8x8 transform ----------
__global__ __launch_bounds__(256) void pc_k(const float* __restrict__ out3, const float* __restrict__ pcw,
                                            const float* __restrict__ pcb, float* __restrict__ u) {
  int n = blockIdx.x * 256 + threadIdx.x;
  if (n >= NCAP) return;
  float pw[64];
  const float4* pwp = (const float4*)(pcw + (size_t)n * 64);
#pragma unroll
  for (int k = 0; k < 16; k++) {
    float4 v = pwp[k];
    pw[4 * k] = v.x; pw[4 * k + 1] = v.y; pw[4 * k + 2] = v.z; pw[4 * k + 3] = v.w;
  }
  float pb[8];
  {
    const float4* pbp = (const float4*)(pcb + (size_t)n * 8);
    float4 a = pbp[0], b = pbp[1];
    pb[0] = a.x; pb[1] = a.y; pb[2] = a.z; pb[3] = a.w;
    pb[4] = b.x; pb[5] = b.y; pb[6] = b.z; pb[7] = b.w;
  }
  for (int b = 0; b < BB; b++) {
    const float4* uip = (const float4*)(out3 + (size_t)b * FLATSZ + (size_t)n * 8);
    float4 a = uip[0], c = uip[1];
    float ui[8] = {a.x, a.y, a.z, a.w, c.x, c.y, c.z, c.w};
    float uo[8];
#pragma unroll
    for (int o = 0; o < 8; o++) uo[o] = pb[o];
#pragma unroll
    for (int i2 = 0; i2 < 8; i2++)
#pragma unroll
      for (int o = 0; o < 8; o++) uo[o] = fmaf(ui[i2], pw[i2 * 8 + o], uo[o]);
    float4* up = (float4*)(u + ((size_t)b * NCAP + n) * 8);
    up[0] = make_float4(uo[0], uo[1], uo[2], uo[3]);
    up[1] = make_float4(uo[4], uo[5], uo[6], uo[7]);
  }
}

// ==========================================================================
// routing v8: MFMA (Guideline 10 — u_hat is matmul-shaped; MfmaUtil was 0).
// Per (n,e): u_hat[16b x 16o] = mfma_f32_16x16x32_f16(A=u[n], B=W[n,e]).
// Operand layout mirrored 1:1 from the VERIFIED conv2_mfma usage:
//   A: row=l&15, k=8(l>>4)+j;  B: col=l&15, k=8(l>>4)+j;  C: col=l&15(o),
//   row=4(l>>4)+r (b).
// MODE 0: s = sum_n u_hat -> pack K=32 = 4n x 8i (full K util, full-wave
//   coalesced loads) and accumulate straight into the MFMA C operand. No
//   VALU math at all.
// MODE 1: per n, 8 MFMAs (K padded: quads 1-3 supply zeros; output still
//   covers all 16 b). o-dot via the 4-DPP butterfly validated in r3-r6
//   (0xB1/0x4E/0x141/0x140 sums the 16-lane row = o); softmax over e fully
//   in-register (8 vals/lane, ZERO DS shuffles). C cached as fp16 pairs
//   (cvt_pkrtz, 16 VGPR) to stay under the 128-VGPR / 4-waves-per-SIMD cap
//   (round-2/4 lesson: spill tripwire = WRITE_SIZE).
// Wave covers all 16 b x 8 n; grid 889; LDS 40KB (32KB reduce + 8KB v)
// -> 4 blocks/CU; atomics unchanged (889 x 2048 = 1.8M).
// ==========================================================================
template <int CTRL>
__device__ __forceinline__ float dpp_add(float x) {
  int y = __builtin_amdgcn_update_dpp(0, __float_as_int(x), CTRL, 0xF, 0xF, true);
  return x + __int_as_float(y);
}

template <int MODE>
__global__ __launch_bounds__(256, 4) void route6_k(const _Float16* __restrict__ uh,
                                                   const _Float16* __restrict__ ech,
                                                   const float* __restrict__ v,
                                                   float* __restrict__ sout) {
  __shared__ float red[8192];    // 32 KB: [wave][2048 slots]
  __shared__ float vlds[2048];   // full v[b*128 + e*16 + o]
  const int t = threadIdx.x, l = t & 63, wv = t >> 6;
  const int q = l >> 4, lo = l & 15;
  const int n0 = blockIdx.x * 32 + wv * 8;

  if (MODE) {
    for (int idx = t; idx < 2048; idx += 256) vlds[idx] = v[idx];
    __syncthreads();
  }

  f32x4 sacc[8];
#pragma unroll
  for (int e = 0; e < 8; e++) sacc[e] = (f32x4){0.f, 0.f, 0.f, 0.f};

  if (MODE == 0) {
    // K=32 = 4n x 8i packed: lane supplies (n=nb+q, i=j); all 64 lanes load.
#pragma unroll 1
    for (int g = 0; g < 2; g++) {
      const int nb = n0 + g * 4;
      h8 a = *(const h8*)(uh + ((size_t)(nb + q) * 16 + lo) * 8);
#pragma unroll
      for (int e = 0; e < 8; e++) {
        h8 b = *(const h8*)(ech + (((size_t)(nb + q) * 8 + e) * 16 + lo) * 8);
        sacc[e] = __builtin_amdgcn_mfma_f32_16x16x32_f16(a, b, sacc[e], 0, 0, 0);
      }
    }
  } else {
    const float* vbase = vlds + q * 512 + lo;   // + r*128 + e*16
#pragma unroll 1
    for (int nn = 0; nn < 8; nn++) {
      const int n = n0 + nn;
      h8 a = h8zero();
      if (l < 16) a = *(const h8*)(uh + ((size_t)n * 16 + lo) * 8);
      uint cpk[8][2];            // u_hat cached as fp16 pairs (16 VGPR)
      float ex[4][8];
      float den[4] = {0.f, 0.f, 0.f, 0.f};
#pragma unroll
      for (int e = 0; e < 8; e++) {
        h8 b = h8zero();
        if (l < 16) b = *(const h8*)(ech + (((size_t)n * 8 + e) * 16 + lo) * 8);
        f32x4 c = __builtin_amdgcn_mfma_f32_16x16x32_f16(a, b, (f32x4){0.f, 0.f, 0.f, 0.f}, 0, 0, 0);
        { f16x2 hh = __builtin_amdgcn_cvt_pkrtz(c[0], c[1]); cpk[e][0] = *(uint*)&hh; }
        { f16x2 hh = __builtin_amdgcn_cvt_pkrtz(c[2], c[3]); cpk[e][1] = *(uint*)&hh; }
#pragma unroll
        for (int r = 0; r < 4; r++) {
          float pr = c[r] * vbase[r * 128 + e * 16];   // u_hat[b=4q+r,e,o=lo]*v
          pr = dpp_add<0xB1>(pr);     // +lane^1 (quad_perm [1,0,3,2])
          pr = dpp_add<0x4E>(pr);     // +lane^2 (quad_perm [2,3,0,1])
          pr = dpp_add<0x141>(pr);    // +lane^4 equiv (row_half_mirror)
          pr = dpp_add<0x140>(pr);    // +lane^8 equiv (row_mirror) -> sum over o
          float exx = __expf(pr);     // no max-subtract (validated r3-r6)
          ex[r][e] = exx;
          den[r] += exx;
        }
      }
      float rd[4];
#pragma unroll
      for (int r = 0; r < 4; r++) rd[r] = __builtin_amdgcn_rcpf(den[r]);
#pragma unroll
      for (int e = 0; e < 8; e++) {
        f16x2 u0 = *(f16x2*)&cpk[e][0];
        f16x2 u1 = *(f16x2*)&cpk[e][1];
        sacc[e][0] = fmaf(ex[0][e] * rd[0], (float)u0.x, sacc[e][0]);
        sacc[e][1] = fmaf(ex[1][e] * rd[1], (float)u0.y, sacc[e][1]);
        sacc[e][2] = fmaf(ex[2][e] * rd[2], (float)u1.x, sacc[e][2]);
        sacc[e][3] = fmaf(ex[3][e] * rd[3], (float)u1.y, sacc[e][3]);
      }
    }
  }

  // block reduce: lane's (e,r) element is slot b*128+e*16+o = (4q+r)*128+e*16+lo
#pragma unroll
  for (int e = 0; e < 8; e++)
#pragma unroll
    for (int r = 0; r < 4; r++)
      red[wv * 2048 + (4 * q + r) * 128 + e * 16 + lo] = sacc[e][r];
  __syncthreads();
#pragma unroll
  for (int m = 0; m < 8; m++) {
    const int slot = t + 256 * m;
    atomicAdd(&sout[slot], red[slot] + red[2048 + slot] + red[4096 + slot] + red[6144 + slot]);
  }
}

// ---------- squash: vout = (vprev? vprev : 0) + squash(s*scale) ----------
__global__ void squash_k(const float* __restrict__ s, float scale, const float* __restrict__ vprev,
                         float* __restrict__ vout) {
  int t = threadIdx.x;   // 128 threads: (b,e)
  const float* sp = s + t * 16;
  float sv[16]; float nn = 0.f;
#pragma unroll
  for (int o = 0; o < 16; o++) { float x = sp[o] * scale; sv[o] = x; nn = fmaf(x, x, nn); }
  float norm = sqrtf(nn);
  float f = nn / (1.f + nn) / (norm + 1e-8f);
#pragma unroll
  for (int o = 0; o < 16; o++) {
    float base = vprev ? vprev[t * 16 + o] : 0.f;
    vout[t * 16 + o] = base + f * sv[o];
  }
}

__global__ void squash_out_k(const float* __restrict__ s, float* __restrict__ out) {
  int t = threadIdx.x;   // 128
  float nn = 0.f;
#pragma unroll
  for (int o = 0; o < 16; o++) { float x = s[t * 16 + o]; nn = fmaf(x, x, nn); }
  float norm = sqrtf(nn);
  float f = nn / (1.f + nn) / (norm + 1e-8f);
  out[t] = f * norm;
}

extern "C" void kernel_launch(void* const* d_in, const int* in_sizes, int n_in,
                              void* d_out, int out_size, void* d_ws, size_t ws_size,
                              hipStream_t stream) {
  const float* x   = (const float*)d_in[0];
  const float* w1  = (const float*)d_in[1];
  const float* b1  = (const float*)d_in[2];
  const float* w2  = (const float*)d_in[3];
  const float* b2  = (const float*)d_in[4];
  const float* w3  = (const float*)d_in[5];
  const float* b3  = (const float*)d_in[6];
  const float* pcw = (const float*)d_in[7];
  const float* pcb = (const float*)d_in[8];
  const float* ecw = (const float*)d_in[9];
  float* out = (float*)d_out;

  float* ws = (float*)d_ws;
  size_t o = 0;
  float* hc   = ws + o; o += 3641344;   // conv1 out fp32 NCHW; later aliased as u
  float* yb   = ws + o; o += 3641344;   // conv2 out fp32 NCHW; later aliased as uh
  float* out3 = ws + o; o += 3641344;   // conv3 out
  ushort* hpc = (ushort*)(ws + o); o += 2568192;   // 16*19*264*64 bf16 NHWC padded
  ushort* wb  = (ushort*)(ws + o); o += 73728;     // 64*2304 bf16
  float* w3t  = ws + o; o += 8192;
  float* s0   = ws + o; o += 2048;
  float* s1   = ws + o; o += 2048;
  float* s2   = ws + o; o += 2048;
  float* v0   = ws + o; o += 2048;
  float* v1   = ws + o; o += 2048;
  uint* ech   = (uint*)(ws + o); o += 14565376;    // 28448*1024 fp16 = 58.3 MB
  float* ub   = hc;                     // lifetime-disjoint alias (pc_k runs after conv3_k)
  _Float16* uhp = (_Float16*)yb;        // lifetime-disjoint alias (cvt_u runs after conv3_k)

  hipMemsetAsync(hpc, 0, (size_t)16 * HPH * HPW2 * 64 * 2, stream);  // zero incl. pad
  hipMemsetAsync(s0, 0, 3 * 2048 * 4, stream);                       // s0|s1|s2 contiguous

  prep_w<<<576, 256, 0, stream>>>(w2, w3, wb, w3t);
  cvt_ec<<<14224, 256, 0, stream>>>(ecw, ech);     // 29.13M floats / 8 per thread
  conv1_k<<<dim3(14, 16), 256, 0, stream>>>(x, w1, b1, hc);
  nhwc_k<<<dim3(4, 14, 16), 256, 0, stream>>>(hc, hpc);
  conv2_mfma<<<dim3(2, 14, 16), 256, 0, stream>>>(hpc, wb, b2, yb);
  conv3_k<<<dim3(4, 14, 16), 256, 0, stream>>>(hc, yb, w3t, b3, out3);
  pc_k<<<112, 256, 0, stream>>>(out3, pcw, pcb, ub);
  cvt_u<<<1778, 256, 0, stream>>>(ub, uhp);        // u -> fp16 [n][b][8]

  const _Float16* echh = (const _Float16*)ech;
  route6_k<0><<<889, 256, 0, stream>>>(uhp, echh, nullptr, s0);
  squash_k<<<1, 128, 0, stream>>>(s0, 0.125f, nullptr, v0);  // c = 1/8 folded in
  route6_k<1><<<889, 256, 0, stream>>>(uhp, echh, v0, s1);
  squash_k<<<1, 128, 0, stream>>>(s1, 1.0f, v0, v1);         // v1 := v0 + squash(s1)  (b_log linearity)
  route6_k<1><<<889, 256, 0, stream>>>(uhp, echh, v1, s2);
  squash_out_k<<<1, 128, 0, stream>>>(s2, out);
}

// Round 8
// 472.622 us; speedup vs baseline: 1.2363x; 1.2363x over previous
//
#include <hip/hip_runtime.h>
#include <hip/hip_bf16.h>
#include <math.h>

#define BB 16
#define H1 14
#define W1 254
#define HPH 19
#define HPW2 264    // padded NHWC width (cols 0..263; data at 2..255)
#define NCAP 28448
#define FLATSZ 227584   // 64*14*254

typedef __attribute__((ext_vector_type(8))) short bf16x8;
typedef __attribute__((ext_vector_type(4))) float f32x4;
typedef __attribute__((ext_vector_type(2))) __fp16 f16x2;   // matches cvt_pkrtz return type
typedef __attribute__((ext_vector_type(8))) _Float16 h8;    // MFMA f16 A/B fragment (4 VGPRs)
typedef __attribute__((ext_vector_type(4))) uint uint4v;

__device__ __forceinline__ ushort f2bf(float f) {
  __hip_bfloat16 h = __float2bfloat16(f);
  return *(ushort*)&h;
}

// ---------- weight prep: wb[co][tap*64+ci] bf16, w3t[c][co] fp32 ----------
__global__ __launch_bounds__(256) void prep_w(const float* __restrict__ w2, const float* __restrict__ w3,
                                              ushort* __restrict__ wb, float* __restrict__ w3t) {
  int idx = blockIdx.x * 256 + threadIdx.x;
  if (idx < 147456) {
    int co = idx / 2304; int rem = idx - co * 2304;
    int tap = rem >> 6; int ci = rem & 63;
    wb[idx] = f2bf(w2[(co * 64 + ci) * 36 + tap]);
  }
  if (idx < 8192) {
    int co = idx & 63; int c = idx >> 6;
    w3t[idx] = w3[co * 128 + c];
  }
}

// ---------- ec_w fp32 -> fp16 (RTZ pack), order-preserving [n][e][o][i] ----------
__global__ __launch_bounds__(256) void cvt_ec(const float* __restrict__ ecw, uint* __restrict__ ech) {
  size_t i = (size_t)blockIdx.x * 256 + threadIdx.x;   // one thread per 8 floats; 3641344 total
  const float4* s = (const float4*)ecw + i * 2;
  float4 a = s[0], b = s[1];
  uint4v pk;
  { f16x2 h = __builtin_amdgcn_cvt_pkrtz(a.x, a.y); pk.x = *(uint*)&h; }
  { f16x2 h = __builtin_amdgcn_cvt_pkrtz(a.z, a.w); pk.y = *(uint*)&h; }
  { f16x2 h = __builtin_amdgcn_cvt_pkrtz(b.x, b.y); pk.z = *(uint*)&h; }
  { f16x2 h = __builtin_amdgcn_cvt_pkrtz(b.z, b.w); pk.w = *(uint*)&h; }
  *((uint4v*)ech + i) = pk;
}

// ---------- u fp32 [b][n][8] -> fp16 [n][b][8] (MFMA A-fragment order) ----------
__global__ __launch_bounds__(256) void cvt_u(const float* __restrict__ u, _Float16* __restrict__ uh) {
  const int idx = blockIdx.x * 256 + threadIdx.x;   // 455168 = NCAP*16 exactly (1778 blocks)
  const int n = idx >> 4, b = idx & 15;
  const float4* s = (const float4*)(u + ((size_t)b * NCAP + n) * 8);
  float4 xa = s[0], xb = s[1];
  h8 o;
  o[0] = (_Float16)xa.x; o[1] = (_Float16)xa.y; o[2] = (_Float16)xa.z; o[3] = (_Float16)xa.w;
  o[4] = (_Float16)xb.x; o[5] = (_Float16)xb.y; o[6] = (_Float16)xb.z; o[7] = (_Float16)xb.w;
  *(h8*)(uh + (size_t)idx * 8) = o;
}

// ---------- conv1: 1->64, 6x6, stride 2 -> compact fp32 hc[b][c][14][254] ----------
__global__ __launch_bounds__(256) void conv1_k(const float* __restrict__ x, const float* __restrict__ w1,
                                               const float* __restrict__ b1, float* __restrict__ hc) {
  const int i = blockIdx.x, b = blockIdx.y;
  __shared__ float xs[6 * 512];
  __shared__ float wsh[2304];
  __shared__ float bsh[64];
  const int t = threadIdx.x;
  for (int idx = t; idx < 6 * 512; idx += 256) {
    int r = idx >> 9, c = idx & 511;
    xs[idx] = x[((size_t)b * 32 + 2 * i + r) * 512 + c];
  }
  for (int idx = t; idx < 2304; idx += 256) wsh[idx] = w1[idx];
  if (t < 64) bsh[t] = b1[t];
  __syncthreads();
  if (t < 254) {
    for (int c = 0; c < 64; c++) {
      float acc = bsh[c];
#pragma unroll
      for (int p = 0; p < 6; p++)
#pragma unroll
        for (int q = 0; q < 6; q++)
          acc = fmaf(xs[p * 512 + 2 * t + q], wsh[c * 36 + p * 6 + q], acc);
      acc = fmaxf(acc, 0.f);
      hc[(((size_t)b * 64 + c) * H1 + i) * W1 + t] = acc;
    }
  }
}

// ---------- transpose hc (NCHW fp32) -> hpc (padded NHWC bf16) ----------
__global__ __launch_bounds__(256) void nhwc_k(const float* __restrict__ hc, ushort* __restrict__ hpc) {
  const int ct = blockIdx.x, i = blockIdx.y, b = blockIdx.z;
  const int c0 = ct * 64;
  __shared__ float ls[64 * 65];
  const int t = threadIdx.x;
  for (int idx = t; idx < 4096; idx += 256) {
    int ci = idx >> 6, cc = idx & 63;
    int c = c0 + cc;
    ls[ci * 65 + cc] = (c < W1) ? hc[(((size_t)b * 64 + ci) * H1 + i) * W1 + c] : 0.f;
  }
  __syncthreads();
  uint* outp = (uint*)hpc;
  for (int idx = t; idx < 2048; idx += 256) {
    int cc = idx >> 5, ci2 = idx & 31;
    int c = c0 + cc;
    if (c < W1) {
      float f0 = ls[(2 * ci2) * 65 + cc];
      float f1 = ls[(2 * ci2 + 1) * 65 + cc];
      uint pk = (uint)f2bf(f0) | ((uint)f2bf(f1) << 16);
      outp[(((size_t)b * HPH + 2 + i) * HPW2 + 2 + c) * 32 + ci2] = pk;
    }
  }
}

// ---------- conv2 implicit-GEMM bf16 MFMA (per-tap LDS double-buffer pipeline) ----------
__device__ __forceinline__ void stage_b(const ushort* __restrict__ wb, ushort* __restrict__ bbuf,
                                        int tap, int w, int l) {
#pragma unroll
  for (int r = 0; r < 2; r++) {
    int v = r * 256 + w * 64 + l;
    int co = v >> 3, s = v & 7;
    int g = s ^ (co & 7);                       // XOR swizzle: slot s holds k-group g
    const ushort* gp = wb + co * 2304 + tap * 64 + g * 8;
    ushort* lp = bbuf + (size_t)(r * 256 + w * 64) * 8;   // wave-uniform base; lane scatters +l*16B
    __builtin_amdgcn_global_load_lds((const uint*)gp, (uint*)lp, 16, 0, 0);
  }
}

__global__ __launch_bounds__(256, 1) void conv2_mfma(const ushort* __restrict__ hpc,
                                                     const ushort* __restrict__ wb,
                                                     const float* __restrict__ b2, float* __restrict__ y) {
  const int b = blockIdx.z, i = blockIdx.y, j0 = blockIdx.x * 128;
  const int t = threadIdx.x;
  const int w = t >> 6, l = t & 63;
  const int lr = l & 15, quad = l >> 4;

  __shared__ ushort bls[2][4096];   // [buf][co*64 + slot*8] bf16, swizzled

  f32x4 acc[2][4];
#pragma unroll
  for (int mt = 0; mt < 2; mt++)
#pragma unroll
    for (int nt = 0; nt < 4; nt++) acc[mt][nt] = (f32x4){0.f, 0.f, 0.f, 0.f};

  const ushort* abase = hpc + (((size_t)b * HPH + i) * HPW2 + (j0 + w * 32 + lr)) * 64 + quad * 8;

  bf16x8 a0[2][2], a1[2][2];   // [ch][mt] for current / next tap

#define ALOAD(dst, tap)                                                        \
  {                                                                            \
    const int p_ = (tap) / 6, q_ = (tap) % 6;                                  \
    const ushort* ap_ = abase + ((size_t)p_ * HPW2 + q_) * 64;                 \
    dst[0][0] = *(const bf16x8*)(ap_);                                         \
    dst[0][1] = *(const bf16x8*)(ap_ + 1024);                                  \
    dst[1][0] = *(const bf16x8*)(ap_ + 32);                                    \
    dst[1][1] = *(const bf16x8*)(ap_ + 32 + 1024);                             \
  }

#define COMPUTE(a, bp)                                                         \
  {                                                                            \
    _Pragma("unroll")                                                          \
    for (int ch = 0; ch < 2; ch++) {                                           \
      const int g2 = ch * 4 + quad;                                            \
      _Pragma("unroll")                                                        \
      for (int nt = 0; nt < 4; nt++) {                                         \
        const int co = nt * 16 + lr;                                           \
        bf16x8 bf = *(const bf16x8*)((bp) + co * 64 + ((g2 ^ (co & 7)) * 8));  \
        acc[0][nt] = __builtin_amdgcn_mfma_f32_16x16x32_bf16(a[ch][0], bf, acc[0][nt], 0, 0, 0); \
        acc[1][nt] = __builtin_amdgcn_mfma_f32_16x16x32_bf16(a[ch][1], bf, acc[1][nt], 0, 0, 0); \
      }                                                                        \
    }                                                                          \
  }

  stage_b(wb, &bls[0][0], 0, w, l);
  __syncthreads();                 // B(0) resident
  ALOAD(a0, 0);

  for (int tp = 0; tp < 36; tp += 2) {
    stage_b(wb, &bls[1][0], tp + 1, w, l);
    ALOAD(a1, tp + 1);
    COMPUTE(a0, &bls[0][0]);
    __syncthreads();
    if (tp + 2 < 36) {
      stage_b(wb, &bls[0][0], tp + 2, w, l);
      ALOAD(a0, tp + 2);
    }
    COMPUTE(a1, &bls[1][0]);
    __syncthreads();
  }

#pragma unroll
  for (int nt = 0; nt < 4; nt++) {
    const int co = nt * 16 + lr;
    const float bias = b2[co];
    float* yrow = y + (((size_t)b * 64 + co) * H1 + i) * W1;
#pragma unroll
    for (int mt = 0; mt < 2; mt++) {
      const int jb = j0 + w * 32 + mt * 16 + quad * 4;
#pragma unroll
      for (int r = 0; r < 4; r++) {
        int j = jb + r;
        if (j < W1) yrow[j] = fmaxf(acc[mt][nt][r] + bias, 0.f);
      }
    }
  }
#undef ALOAD
#undef COMPUTE
}

// ---------- conv3: 1x1, 128->64, over concat(hc, y); NO relu ----------
__global__ __launch_bounds__(256) void conv3_k(const float* __restrict__ hc, const float* __restrict__ y,
                                               const float* __restrict__ w3t, const float* __restrict__ b3,
                                               float* __restrict__ out3) {
  const int b = blockIdx.z, i = blockIdx.y, j0 = blockIdx.x * 64;
  __shared__ float cs[32][64];
  __shared__ float wsh[32][64];
  const int t = threadIdx.x;
  const int cog = t >> 4, jg = t & 15;
  float acc[4][4];
#pragma unroll
  for (int a = 0; a < 4; a++)
#pragma unroll
    for (int j = 0; j < 4; j++) acc[a][j] = 0.f;

  for (int ch = 0; ch < 4; ch++) {
    __syncthreads();
    for (int idx = t; idx < 2048; idx += 256) {
      int cl = idx >> 6; int j = j0 + (idx & 63);
      int c = ch * 32 + cl;
      float v = 0.f;
      if (j < W1) {
        if (c < 64) v = hc[(((size_t)b * 64 + c) * H1 + i) * W1 + j];
        else        v = y[(((size_t)b * 64 + (c - 64)) * H1 + i) * W1 + j];
      }
      cs[cl][idx & 63] = v;
    }
    for (int idx = t; idx < 2048; idx += 256)
      wsh[idx >> 6][idx & 63] = w3t[(ch * 32 + (idx >> 6)) * 64 + (idx & 63)];
    __syncthreads();
#pragma unroll
    for (int c = 0; c < 32; c++) {
      float4 xv = *(const float4*)&cs[c][jg * 4];
      float4 wv = *(const float4*)&wsh[c][cog * 4];
#pragma unroll
      for (int jj = 0; jj < 4; jj++) {
        float xx = (&xv.x)[jj];
        acc[0][jj] = fmaf(wv.x, xx, acc[0][jj]);
        acc[1][jj] = fmaf(wv.y, xx, acc[1][jj]);
        acc[2][jj] = fmaf(wv.z, xx, acc[2][jj]);
        acc[3][jj] = fmaf(wv.w, xx, acc[3][jj]);
      }
    }
  }
#pragma unroll
  for (int a = 0; a < 4; a++) {
    int co = cog * 4 + a;
    float bias = b3[co];
#pragma unroll
    for (int jj = 0; jj < 4; jj++) {
      int j = j0 + jg * 4 + jj;
      if (j < W1) out3[(((size_t)b * 64 + co) * H1 + i) * W1 + j] = acc[a][jj] + bias;
    }
  }
}

// ---------- pc: per-capsule 8x8 transform ----------
__global__ __launch_bounds__(256) void pc_k(const float* __restrict__ out3, const float* __restrict__ pcw,
                                            const float* __restrict__ pcb, float* __restrict__ u) {
  int n = blockIdx.x * 256 + threadIdx.x;
  if (n >= NCAP) return;
  float pw[64];
  const float4* pwp = (const float4*)(pcw + (size_t)n * 64);
#pragma unroll
  for (int k = 0; k < 16; k++) {
    float4 v = pwp[k];
    pw[4 * k] = v.x; pw[4 * k + 1] = v.y; pw[4 * k + 2] = v.z; pw[4 * k + 3] = v.w;
  }
  float pb[8];
  {
    const float4* pbp = (const float4*)(pcb + (size_t)n * 8);
    float4 a = pbp[0], b = pbp[1];
    pb[0] = a.x; pb[1] = a.y; pb[2] = a.z; pb[3] = a.w;
    pb[4] = b.x; pb[5] = b.y; pb[6] = b.z; pb[7] = b.w;
  }
  for (int b = 0; b < BB; b++) {
    const float4* uip = (const float4*)(out3 + (size_t)b * FLATSZ + (size_t)n * 8);
    float4 a = uip[0], c = uip[1];
    float ui[8] = {a.x, a.y, a.z, a.w, c.x, c.y, c.z, c.w};
    float uo[8];
#pragma unroll
    for (int o = 0; o < 8; o++) uo[o] = pb[o];
#pragma unroll
    for (int i2 = 0; i2 < 8; i2++)
#pragma unroll
      for (int o = 0; o < 8; o++) uo[o] = fmaf(ui[i2], pw[i2 * 8 + o], uo[o]);
    float4* up = (float4*)(u + ((size_t)b * NCAP + n) * 8);
    up[0] = make_float4(uo[0], uo[1], uo[2], uo[3]);
    up[1] = make_float4(uo[4], uo[5], uo[6], uo[7]);
  }
}

// ==========================================================================
// routing v9:
// route_s0 (iter 0): streaming MFMA GEMM, VALIDATED in round 7 (absmax 0.0,
//   not in top-5 -> fast). s = sum_n u_hat with K=32 = 4n x 8i packed; all
//   64 lanes load; accumulate straight into MFMA C. No VALU math.
// route_s1 (iters 1-2): round-6-validated VALU body (fp16 ec, DPP softmax,
//   no max-subtract) with the DS pipe cut 5 -> 3 ops per (n,bb):
//   - v hoisted into 16 regs (n-invariant; the per-(n,bb) ds_read_b64 was
//     pure waste) -> vlds gone, LDS 16 KB.
//   - ^32 shuffle via v_permlane32_swap (VALU) instead of ds_bpermute
//     (__has_builtin guard falls back to bpermute).
//   Remaining DS: 2x ds_read_b128 u-broadcast + 1x ds_swizzle ^16.
//   Reg estimate ~85 < 128 cap at (256,4); spill tripwire = WRITE_SIZE.
// ==========================================================================
template <int CTRL>
__device__ __forceinline__ float dpp_add(float x) {
  int y = __builtin_amdgcn_update_dpp(0, __float_as_int(x), CTRL, 0xF, 0xF, true);
  return x + __int_as_float(y);
}

__device__ __forceinline__ float xor32_partner(float x, bool low) {
#if __has_builtin(__builtin_amdgcn_permlane32_swap)
  auto r = __builtin_amdgcn_permlane32_swap(__float_as_uint(x), __float_as_uint(x), false, false);
  return __uint_as_float(low ? r[1] : r[0]);   // lanes<32 partner in ret1, lanes>=32 in ret0
#else
  return __uint_as_float((uint)__builtin_amdgcn_ds_bpermute(
      (int)((((threadIdx.x & 63) ^ 32) << 2)), (int)__float_as_uint(x)));
#endif
}

__global__ __launch_bounds__(256, 4) void route_s0(const _Float16* __restrict__ uh,
                                                   const _Float16* __restrict__ ech,
                                                   float* __restrict__ sout) {
  __shared__ float red[8192];    // 32 KB: [wave][2048 slots]
  const int t = threadIdx.x, l = t & 63, wv = t >> 6;
  const int q = l >> 4, lo = l & 15;
  const int n0 = blockIdx.x * 32 + wv * 8;

  f32x4 sacc[8];
#pragma unroll
  for (int e = 0; e < 8; e++) sacc[e] = (f32x4){0.f, 0.f, 0.f, 0.f};

  // K=32 = 4n x 8i packed: lane supplies (n=nb+q, i=j); all 64 lanes load.
#pragma unroll 1
  for (int g = 0; g < 2; g++) {
    const int nb = n0 + g * 4;
    h8 a = *(const h8*)(uh + ((size_t)(nb + q) * 16 + lo) * 8);
#pragma unroll
    for (int e = 0; e < 8; e++) {
      h8 b = *(const h8*)(ech + (((size_t)(nb + q) * 8 + e) * 16 + lo) * 8);
      sacc[e] = __builtin_amdgcn_mfma_f32_16x16x32_f16(a, b, sacc[e], 0, 0, 0);
    }
  }

  // lane's (e,r) element is slot b*128+e*16+o = (4q+r)*128+e*16+lo
#pragma unroll
  for (int e = 0; e < 8; e++)
#pragma unroll
    for (int r = 0; r < 4; r++)
      red[wv * 2048 + (4 * q + r) * 128 + e * 16 + lo] = sacc[e][r];
  __syncthreads();
#pragma unroll
  for (int m = 0; m < 8; m++) {
    const int slot = t + 256 * m;
    atomicAdd(&sout[slot], red[slot] + red[2048 + slot] + red[4096 + slot] + red[6144 + slot]);
  }
}

__global__ __launch_bounds__(256, 4) void route_s1(const float* __restrict__ u, const uint* __restrict__ ech,
                                                   const float* __restrict__ v, float* __restrict__ sout) {
  __shared__ float red[4096];    // 16 KB reduce scratch; first 8 KB doubles as us[]
  float* us = red;               // us[wv*512 + bb*64 + nn*8 + i]

  const int t = threadIdx.x, l = t & 63, wv = t >> 6;
  const int b0 = blockIdx.y * 8;
  const int n0 = blockIdx.x * 32 + wv * 8;
  const bool low = l < 32;

  // v into 16 regs: lane l needs v[b][e=l>>3][o0=2(l&7)] pair = v[b*128 + 2l]
  float2 vv[8];
#pragma unroll
  for (int bb = 0; bb < 8; bb++)
    vv[bb] = *(const float2*)&v[(size_t)(b0 + bb) * 128 + 2 * l];

  // stage u slab: 8 b x (8 n x 8 i); wave-private region -> lgkmcnt wait suffices
#pragma unroll
  for (int bb = 0; bb < 8; bb++)
    us[wv * 512 + bb * 64 + l] = u[((size_t)(b0 + bb) * NCAP + n0) * 8 + l];

  float sacc[16];
#pragma unroll
  for (int k = 0; k < 16; k++) sacc[k] = 0.f;

  // lane l holds ec_w[n] halves [16l,16l+16): W[e=l>>3][o0=2(l&7)][i0..7], W[e][o0+1][i0..7]
  const uint4v* hbase = (const uint4v*)(ech + (size_t)n0 * 512) + (l * 2);

  auto proc = [&](int nn, uint4v w0, uint4v w1) {
    float ec[16];
#pragma unroll
    for (int k = 0; k < 4; k++) {
      uint t0 = w0[k], t1 = w1[k];
      f16x2 a = *(f16x2*)&t0;
      f16x2 b = *(f16x2*)&t1;
      ec[2 * k]     = (float)a.x; ec[2 * k + 1] = (float)a.y;
      ec[8 + 2 * k] = (float)b.x; ec[8 + 2 * k + 1] = (float)b.y;
    }
#pragma unroll
    for (int bb = 0; bb < 8; bb++) {
      const float4* up = (const float4*)&us[wv * 512 + bb * 64 + nn * 8];  // same addr all lanes: broadcast
      const float4 ua = up[0], ub = up[1];
      const float uv[8] = {ua.x, ua.y, ua.z, ua.w, ub.x, ub.y, ub.z, ub.w};
      float h0 = 0.f, h1 = 0.f;
#pragma unroll
      for (int k = 0; k < 8; k++) {
        h0 = fmaf(ec[k], uv[k], h0);        // u_hat[b,n,e,o0]
        h1 = fmaf(ec[8 + k], uv[k], h1);    // u_hat[b,n,e,o0+1]
      }
      float p = fmaf(h0, vv[bb].x, h1 * vv[bb].y);
      p = dpp_add<0xB1>(p);    // + lane^1 (quad_perm [1,0,3,2])
      p = dpp_add<0x4E>(p);    // + lane^2 (quad_perm [2,3,0,1])
      p = dpp_add<0x141>(p);   // + lane^4 equiv (row_half_mirror after quad sums)
      const float ex = __expf(p);          // no max-subtract: |b_log| tiny (validated)
      float den = dpp_add<0x140>(ex);      // + lane^8 equiv (row_mirror)
      den += __int_as_float(__builtin_amdgcn_ds_swizzle(__float_as_int(den), 0x401F)); // ^16
      den += xor32_partner(den, low);                                                  // ^32 (VALU)
      const float cc = ex * __builtin_amdgcn_rcpf(den);
      sacc[2 * bb] = fmaf(cc, h0, sacc[2 * bb]);
      sacc[2 * bb + 1] = fmaf(cc, h1, sacc[2 * bb + 1]);
    }
  };

  // nn loop, pinned 2-unrolled with 1-ahead ec register double-buffer (8 regs)
  uint4v ca0 = hbase[0], ca1 = hbase[1];
#pragma unroll 1
  for (int nn = 0; nn < 8; nn += 2) {
    const uint4v* pb = hbase + (size_t)(nn + 1) * 128;
    uint4v cb0 = pb[0], cb1 = pb[1];
    proc(nn, ca0, ca1);
    if (nn + 2 < 8) {
      const uint4v* pa = hbase + (size_t)(nn + 2) * 128;
      ca0 = pa[0]; ca1 = pa[1];
    }
    proc(nn + 1, cb0, cb1);
  }

  // transposed conflict-free block reduce -> one atomic per slot
  __syncthreads();               // all us reads done before clobbering red (alias!)
#pragma unroll
  for (int k = 0; k < 16; k++) red[k * 256 + wv * 64 + l] = sacc[k];
  __syncthreads();
#pragma unroll
  for (int m = 0; m < 4; m++) {
    int slot = t + 256 * m;                       // slot = bl*128 + eo  (bl in [0,8))
    int bl = slot >> 7, eo = slot & 127;
    int k = 2 * bl + (eo & 1), l2 = eo >> 1;
    const float* r = red + k * 256 + l2;
    atomicAdd(&sout[(b0 + bl) * 128 + eo], r[0] + r[64] + r[128] + r[192]);
  }
}

// ---------- squash: vout = (vprev? vprev : 0) + squash(s*scale) ----------
__global__ void squash_k(const float* __restrict__ s, float scale, const float* __restrict__ vprev,
                         float* __restrict__ vout) {
  int t = threadIdx.x;   // 128 threads: (b,e)
  const float* sp = s + t * 16;
  float sv[16]; float nn = 0.f;
#pragma unroll
  for (int o = 0; o < 16; o++) { float x = sp[o] * scale; sv[o] = x; nn = fmaf(x, x, nn); }
  float norm = sqrtf(nn);
  float f = nn / (1.f + nn) / (norm + 1e-8f);
#pragma unroll
  for (int o = 0; o < 16; o++) {
    float base = vprev ? vprev[t * 16 + o] : 0.f;
    vout[t * 16 + o] = base + f * sv[o];
  }
}

__global__ void squash_out_k(const float* __restrict__ s, float* __restrict__ out) {
  int t = threadIdx.x;   // 128
  float nn = 0.f;
#pragma unroll
  for (int o = 0; o < 16; o++) { float x = s[t * 16 + o]; nn = fmaf(x, x, nn); }
  float norm = sqrtf(nn);
  float f = nn / (1.f + nn) / (norm + 1e-8f);
  out[t] = f * norm;
}

extern "C" void kernel_launch(void* const* d_in, const int* in_sizes, int n_in,
                              void* d_out, int out_size, void* d_ws, size_t ws_size,
                              hipStream_t stream) {
  const float* x   = (const float*)d_in[0];
  const float* w1  = (const float*)d_in[1];
  const float* b1  = (const float*)d_in[2];
  const float* w2  = (const float*)d_in[3];
  const float* b2  = (const float*)d_in[4];
  const float* w3  = (const float*)d_in[5];
  const float* b3  = (const float*)d_in[6];
  const float* pcw = (const float*)d_in[7];
  const float* pcb = (const float*)d_in[8];
  const float* ecw = (const float*)d_in[9];
  float* out = (float*)d_out;

  float* ws = (float*)d_ws;
  size_t o = 0;
  float* hc   = ws + o; o += 3641344;   // conv1 out fp32 NCHW; later aliased as u
  float* yb   = ws + o; o += 3641344;   // conv2 out fp32 NCHW; later aliased as uh
  float* out3 = ws + o; o += 3641344;   // conv3 out
  ushort* hpc = (ushort*)(ws + o); o += 2568192;   // 16*19*264*64 bf16 NHWC padded
  ushort* wb  = (ushort*)(ws + o); o += 73728;     // 64*2304 bf16
  float* w3t  = ws + o; o += 8192;
  float* s0   = ws + o; o += 2048;
  float* s1   = ws + o; o += 2048;
  float* s2   = ws + o; o += 2048;
  float* v0   = ws + o; o += 2048;
  float* v1   = ws + o; o += 2048;
  uint* ech   = (uint*)(ws + o); o += 14565376;    // 28448*1024 fp16 = 58.3 MB
  float* ub   = hc;                     // lifetime-disjoint alias (pc_k runs after conv3_k)
  _Float16* uhp = (_Float16*)yb;        // lifetime-disjoint alias (cvt_u runs after conv3_k)

  hipMemsetAsync(hpc, 0, (size_t)16 * HPH * HPW2 * 64 * 2, stream);  // zero incl. pad
  hipMemsetAsync(s0, 0, 3 * 2048 * 4, stream);                       // s0|s1|s2 contiguous

  prep_w<<<576, 256, 0, stream>>>(w2, w3, wb, w3t);
  cvt_ec<<<14224, 256, 0, stream>>>(ecw, ech);     // 29.13M floats / 8 per thread
  conv1_k<<<dim3(14, 16), 256, 0, stream>>>(x, w1, b1, hc);
  nhwc_k<<<dim3(4, 14, 16), 256, 0, stream>>>(hc, hpc);
  conv2_mfma<<<dim3(2, 14, 16), 256, 0, stream>>>(hpc, wb, b2, yb);
  conv3_k<<<dim3(4, 14, 16), 256, 0, stream>>>(hc, yb, w3t, b3, out3);
  pc_k<<<112, 256, 0, stream>>>(out3, pcw, pcb, ub);
  cvt_u<<<1778, 256, 0, stream>>>(ub, uhp);        // u -> fp16 [n][b][8]

  route_s0<<<889, 256, 0, stream>>>(uhp, (const _Float16*)ech, s0);
  squash_k<<<1, 128, 0, stream>>>(s0, 0.125f, nullptr, v0);  // c = 1/8 folded in
  route_s1<<<dim3(889, 2), 256, 0, stream>>>(ub, ech, v0, s1);
  squash_k<<<1, 128, 0, stream>>>(s1, 1.0f, v0, v1);         // v1 := v0 + squash(s1)  (b_log linearity)
  route_s1<<<dim3(889, 2), 256, 0, stream>>>(ub, ech, v1, s2);
  squash_out_k<<<1, 128, 0, stream>>>(s2, out);
}

// Round 9
// 443.360 us; speedup vs baseline: 1.3179x; 1.0660x over previous
//
#include <hip/hip_runtime.h>
#include <hip/hip_bf16.h>
#include <math.h>

#define BB 16
#define H1 14
#define W1 254
#define HPH 19
#define HPW2 264    // padded NHWC width (cols 0..263; data at 2..255)
#define NCAP 28448
#define FLATSZ 227584   // 64*14*254

typedef __attribute__((ext_vector_type(8))) short bf16x8;
typedef __attribute__((ext_vector_type(4))) float f32x4;
typedef __attribute__((ext_vector_type(2))) __fp16 f16x2;   // matches cvt_pkrtz return type
typedef __attribute__((ext_vector_type(8))) _Float16 h8;    // MFMA f16 A/B fragment (4 VGPRs)
typedef __attribute__((ext_vector_type(4))) uint uint4v;

__device__ __forceinline__ ushort f2bf(float f) {
  __hip_bfloat16 h = __float2bfloat16(f);
  return *(ushort*)&h;
}

// ---------- weight prep: wb[co][tap*64+ci] bf16, w3t[c][co] fp32 ----------
__global__ __launch_bounds__(256) void prep_w(const float* __restrict__ w2, const float* __restrict__ w3,
                                              ushort* __restrict__ wb, float* __restrict__ w3t) {
  int idx = blockIdx.x * 256 + threadIdx.x;
  if (idx < 147456) {
    int co = idx / 2304; int rem = idx - co * 2304;
    int tap = rem >> 6; int ci = rem & 63;
    wb[idx] = f2bf(w2[(co * 64 + ci) * 36 + tap]);
  }
  if (idx < 8192) {
    int co = idx & 63; int c = idx >> 6;
    w3t[idx] = w3[co * 128 + c];
  }
}

// ---------- u fp32 [b][n][8] -> fp16 [n][b][8] (MFMA A-fragment order) ----------
__global__ __launch_bounds__(256) void cvt_u(const float* __restrict__ u, _Float16* __restrict__ uh) {
  const int idx = blockIdx.x * 256 + threadIdx.x;   // 455168 = NCAP*16 exactly (1778 blocks)
  const int n = idx >> 4, b = idx & 15;
  const float4* s = (const float4*)(u + ((size_t)b * NCAP + n) * 8);
  float4 xa = s[0], xb = s[1];
  h8 o;
  o[0] = (_Float16)xa.x; o[1] = (_Float16)xa.y; o[2] = (_Float16)xa.z; o[3] = (_Float16)xa.w;
  o[4] = (_Float16)xb.x; o[5] = (_Float16)xb.y; o[6] = (_Float16)xb.z; o[7] = (_Float16)xb.w;
  *(h8*)(uh + (size_t)idx * 8) = o;
}

// ---------- conv1: 1->64, 6x6, stride 2 -> compact fp32 hc[b][c][14][254] ----------
__global__ __launch_bounds__(256) void conv1_k(const float* __restrict__ x, const float* __restrict__ w1,
                                               const float* __restrict__ b1, float* __restrict__ hc) {
  const int i = blockIdx.x, b = blockIdx.y;
  __shared__ float xs[6 * 512];
  __shared__ float wsh[2304];
  __shared__ float bsh[64];
  const int t = threadIdx.x;
  for (int idx = t; idx < 6 * 512; idx += 256) {
    int r = idx >> 9, c = idx & 511;
    xs[idx] = x[((size_t)b * 32 + 2 * i + r) * 512 + c];
  }
  for (int idx = t; idx < 2304; idx += 256) wsh[idx] = w1[idx];
  if (t < 64) bsh[t] = b1[t];
  __syncthreads();
  if (t < 254) {
    for (int c = 0; c < 64; c++) {
      float acc = bsh[c];
#pragma unroll
      for (int p = 0; p < 6; p++)
#pragma unroll
        for (int q = 0; q < 6; q++)
          acc = fmaf(xs[p * 512 + 2 * t + q], wsh[c * 36 + p * 6 + q], acc);
      acc = fmaxf(acc, 0.f);
      hc[(((size_t)b * 64 + c) * H1 + i) * W1 + t] = acc;
    }
  }
}

// ---------- transpose hc (NCHW fp32) -> hpc (padded NHWC bf16) ----------
__global__ __launch_bounds__(256) void nhwc_k(const float* __restrict__ hc, ushort* __restrict__ hpc) {
  const int ct = blockIdx.x, i = blockIdx.y, b = blockIdx.z;
  const int c0 = ct * 64;
  __shared__ float ls[64 * 65];
  const int t = threadIdx.x;
  for (int idx = t; idx < 4096; idx += 256) {
    int ci = idx >> 6, cc = idx & 63;
    int c = c0 + cc;
    ls[ci * 65 + cc] = (c < W1) ? hc[(((size_t)b * 64 + ci) * H1 + i) * W1 + c] : 0.f;
  }
  __syncthreads();
  uint* outp = (uint*)hpc;
  for (int idx = t; idx < 2048; idx += 256) {
    int cc = idx >> 5, ci2 = idx & 31;
    int c = c0 + cc;
    if (c < W1) {
      float f0 = ls[(2 * ci2) * 65 + cc];
      float f1 = ls[(2 * ci2 + 1) * 65 + cc];
      uint pk = (uint)f2bf(f0) | ((uint)f2bf(f1) << 16);
      outp[(((size_t)b * HPH + 2 + i) * HPW2 + 2 + c) * 32 + ci2] = pk;
    }
  }
}

// ---------- conv2 implicit-GEMM bf16 MFMA (per-tap LDS double-buffer pipeline) ----------
__device__ __forceinline__ void stage_b(const ushort* __restrict__ wb, ushort* __restrict__ bbuf,
                                        int tap, int w, int l) {
#pragma unroll
  for (int r = 0; r < 2; r++) {
    int v = r * 256 + w * 64 + l;
    int co = v >> 3, s = v & 7;
    int g = s ^ (co & 7);                       // XOR swizzle: slot s holds k-group g
    const ushort* gp = wb + co * 2304 + tap * 64 + g * 8;
    ushort* lp = bbuf + (size_t)(r * 256 + w * 64) * 8;   // wave-uniform base; lane scatters +l*16B
    __builtin_amdgcn_global_load_lds((const uint*)gp, (uint*)lp, 16, 0, 0);
  }
}

__global__ __launch_bounds__(256, 1) void conv2_mfma(const ushort* __restrict__ hpc,
                                                     const ushort* __restrict__ wb,
                                                     const float* __restrict__ b2, float* __restrict__ y) {
  const int b = blockIdx.z, i = blockIdx.y, j0 = blockIdx.x * 128;
  const int t = threadIdx.x;
  const int w = t >> 6, l = t & 63;
  const int lr = l & 15, quad = l >> 4;

  __shared__ ushort bls[2][4096];   // [buf][co*64 + slot*8] bf16, swizzled

  f32x4 acc[2][4];
#pragma unroll
  for (int mt = 0; mt < 2; mt++)
#pragma unroll
    for (int nt = 0; nt < 4; nt++) acc[mt][nt] = (f32x4){0.f, 0.f, 0.f, 0.f};

  const ushort* abase = hpc + (((size_t)b * HPH + i) * HPW2 + (j0 + w * 32 + lr)) * 64 + quad * 8;

  bf16x8 a0[2][2], a1[2][2];   // [ch][mt] for current / next tap

#define ALOAD(dst, tap)                                                        \
  {                                                                            \
    const int p_ = (tap) / 6, q_ = (tap) % 6;                                  \
    const ushort* ap_ = abase + ((size_t)p_ * HPW2 + q_) * 64;                 \
    dst[0][0] = *(const bf16x8*)(ap_);                                         \
    dst[0][1] = *(const bf16x8*)(ap_ + 1024);                                  \
    dst[1][0] = *(const bf16x8*)(ap_ + 32);                                    \
    dst[1][1] = *(const bf16x8*)(ap_ + 32 + 1024);                             \
  }

#define COMPUTE(a, bp)                                                         \
  {                                                                            \
    _Pragma("unroll")                                                          \
    for (int ch = 0; ch < 2; ch++) {                                           \
      const int g2 = ch * 4 + quad;                                            \
      _Pragma("unroll")                                                        \
      for (int nt = 0; nt < 4; nt++) {                                         \
        const int co = nt * 16 + lr;                                           \
        bf16x8 bf = *(const bf16x8*)((bp) + co * 64 + ((g2 ^ (co & 7)) * 8));  \
        acc[0][nt] = __builtin_amdgcn_mfma_f32_16x16x32_bf16(a[ch][0], bf, acc[0][nt], 0, 0, 0); \
        acc[1][nt] = __builtin_amdgcn_mfma_f32_16x16x32_bf16(a[ch][1], bf, acc[1][nt], 0, 0, 0); \
      }                                                                        \
    }                                                                          \
  }

  stage_b(wb, &bls[0][0], 0, w, l);
  __syncthreads();                 // B(0) resident
  ALOAD(a0, 0);

  for (int tp = 0; tp < 36; tp += 2) {
    stage_b(wb, &bls[1][0], tp + 1, w, l);
    ALOAD(a1, tp + 1);
    COMPUTE(a0, &bls[0][0]);
    __syncthreads();
    if (tp + 2 < 36) {
      stage_b(wb, &bls[0][0], tp + 2, w, l);
      ALOAD(a0, tp + 2);
    }
    COMPUTE(a1, &bls[1][0]);
    __syncthreads();
  }

#pragma unroll
  for (int nt = 0; nt < 4; nt++) {
    const int co = nt * 16 + lr;
    const float bias = b2[co];
    float* yrow = y + (((size_t)b * 64 + co) * H1 + i) * W1;
#pragma unroll
    for (int mt = 0; mt < 2; mt++) {
      const int jb = j0 + w * 32 + mt * 16 + quad * 4;
#pragma unroll
      for (int r = 0; r < 4; r++) {
        int j = jb + r;
        if (j < W1) yrow[j] = fmaxf(acc[mt][nt][r] + bias, 0.f);
      }
    }
  }
#undef ALOAD
#undef COMPUTE
}

// ---------- conv3: 1x1, 128->64, over concat(hc, y); NO relu ----------
__global__ __launch_bounds__(256) void conv3_k(const float* __restrict__ hc, const float* __restrict__ y,
                                               const float* __restrict__ w3t, const float* __restrict__ b3,
                                               float* __restrict__ out3) {
  const int b = blockIdx.z, i = blockIdx.y, j0 = blockIdx.x * 64;
  __shared__ float cs[32][64];
  __shared__ float wsh[32][64];
  const int t = threadIdx.x;
  const int cog = t >> 4, jg = t & 15;
  float acc[4][4];
#pragma unroll
  for (int a = 0; a < 4; a++)
#pragma unroll
    for (int j = 0; j < 4; j++) acc[a][j] = 0.f;

  for (int ch = 0; ch < 4; ch++) {
    __syncthreads();
    for (int idx = t; idx < 2048; idx += 256) {
      int cl = idx >> 6; int j = j0 + (idx & 63);
      int c = ch * 32 + cl;
      float v = 0.f;
      if (j < W1) {
        if (c < 64) v = hc[(((size_t)b * 64 + c) * H1 + i) * W1 + j];
        else        v = y[(((size_t)b * 64 + (c - 64)) * H1 + i) * W1 + j];
      }
      cs[cl][idx & 63] = v;
    }
    for (int idx = t; idx < 2048; idx += 256)
      wsh[idx >> 6][idx & 63] = w3t[(ch * 32 + (idx >> 6)) * 64 + (idx & 63)];
    __syncthreads();
#pragma unroll
    for (int c = 0; c < 32; c++) {
      float4 xv = *(const float4*)&cs[c][jg * 4];
      float4 wv = *(const float4*)&wsh[c][cog * 4];
#pragma unroll
      for (int jj = 0; jj < 4; jj++) {
        float xx = (&xv.x)[jj];
        acc[0][jj] = fmaf(wv.x, xx, acc[0][jj]);
        acc[1][jj] = fmaf(wv.y, xx, acc[1][jj]);
        acc[2][jj] = fmaf(wv.z, xx, acc[2][jj]);
        acc[3][jj] = fmaf(wv.w, xx, acc[3][jj]);
      }
    }
  }
#pragma unroll
  for (int a = 0; a < 4; a++) {
    int co = cog * 4 + a;
    float bias = b3[co];
#pragma unroll
    for (int jj = 0; jj < 4; jj++) {
      int j = j0 + jg * 4 + jj;
      if (j < W1) out3[(((size_t)b * 64 + co) * H1 + i) * W1 + j] = acc[a][jj] + bias;
    }
  }
}

// ---------- pc: per-capsule 8x8 transform; b-loop split over blockIdx.y (TLP) ----------
__global__ __launch_bounds__(256) void pc_k(const float* __restrict__ out3, const float* __restrict__ pcw,
                                            const float* __restrict__ pcb, float* __restrict__ u) {
  int n = blockIdx.x * 256 + threadIdx.x;
  if (n >= NCAP) return;
  const int bb0 = blockIdx.y * 8;
  float pw[64];
  const float4* pwp = (const float4*)(pcw + (size_t)n * 64);
#pragma unroll
  for (int k = 0; k < 16; k++) {
    float4 v = pwp[k];
    pw[4 * k] = v.x; pw[4 * k + 1] = v.y; pw[4 * k + 2] = v.z; pw[4 * k + 3] = v.w;
  }
  float pb[8];
  {
    const float4* pbp = (const float4*)(pcb + (size_t)n * 8);
    float4 a = pbp[0], b = pbp[1];
    pb[0] = a.x; pb[1] = a.y; pb[2] = a.z; pb[3] = a.w;
    pb[4] = b.x; pb[5] = b.y; pb[6] = b.z; pb[7] = b.w;
  }
  for (int b = bb0; b < bb0 + 8; b++) {
    const float4* uip = (const float4*)(out3 + (size_t)b * FLATSZ + (size_t)n * 8);
    float4 a = uip[0], c = uip[1];
    float ui[8] = {a.x, a.y, a.z, a.w, c.x, c.y, c.z, c.w};
    float uo[8];
#pragma unroll
    for (int o = 0; o < 8; o++) uo[o] = pb[o];
#pragma unroll
    for (int i2 = 0; i2 < 8; i2++)
#pragma unroll
      for (int o = 0; o < 8; o++) uo[o] = fmaf(ui[i2], pw[i2 * 8 + o], uo[o]);
    float4* up = (float4*)(u + ((size_t)b * NCAP + n) * 8);
    up[0] = make_float4(uo[0], uo[1], uo[2], uo[3]);
    up[1] = make_float4(uo[4], uo[5], uo[6], uo[7]);
  }
}

// ==========================================================================
// routing v10:
// route_cvt0 (iter 0): round-7/8-validated streaming MFMA GEMM, now FUSED
//   with the ec fp32->fp16 conversion: reads ecw fp32 ONCE (116 MB), converts
//   in-register (cvt_pkrtz, element mapping identical to the validated
//   cvt_ec), STORES ech fp16 for passes 1-2, and feeds the MFMA directly.
//   Kills the separate 174 MB cvt_ec pass. WRITE_SIZE ~65 MB here is LEGIT
//   (ech stores + atomics), not spill.
// route_s1 (iters 1-2): round-8-validated body (fp16 ec, DPP softmax, v in
//   registers, permlane ^32, no max-subtract), now with squash FUSED at
//   kernel entry: v computed in-register from s0 (and s1 for pass 2) via
//   the same DPP o-butterfly. Kills both squash_k dispatches. Stream order
//   guarantees s visibility. Spill tripwire: WRITE_SIZE must stay ~7 MB.
// ==========================================================================
template <int CTRL>
__device__ __forceinline__ float dpp_add(float x) {
  int y = __builtin_amdgcn_update_dpp(0, __float_as_int(x), CTRL, 0xF, 0xF, true);
  return x + __int_as_float(y);
}

__device__ __forceinline__ float xor32_partner(float x, bool low) {
#if __has_builtin(__builtin_amdgcn_permlane32_swap)
  auto r = __builtin_amdgcn_permlane32_swap(__float_as_uint(x), __float_as_uint(x), false, false);
  return __uint_as_float(low ? r[1] : r[0]);   // lanes<32 partner in ret1, lanes>=32 in ret0
#else
  return __uint_as_float((uint)__builtin_amdgcn_ds_bpermute(
      (int)((((threadIdx.x & 63) ^ 32) << 2)), (int)__float_as_uint(x)));
#endif
}

__global__ __launch_bounds__(256, 4) void route_cvt0(const _Float16* __restrict__ uh,
                                                     const float* __restrict__ ecw,
                                                     uint4v* __restrict__ ech4,
                                                     float* __restrict__ sout) {
  __shared__ float red[8192];    // 32 KB: [wave][2048 slots]
  const int t = threadIdx.x, l = t & 63, wv = t >> 6;
  const int q = l >> 4, lo = l & 15;
  const int n0 = blockIdx.x * 32 + wv * 8;

  f32x4 sacc[8];
#pragma unroll
  for (int e = 0; e < 8; e++) sacc[e] = (f32x4){0.f, 0.f, 0.f, 0.f};

  // K=32 = 4n x 8i packed: lane supplies (n=nb+q, i=j); all 64 lanes load.
#pragma unroll 1
  for (int g = 0; g < 2; g++) {
    const int n = n0 + g * 4 + q;
    h8 a = *(const h8*)(uh + ((size_t)n * 16 + lo) * 8);
#pragma unroll
    for (int e = 0; e < 8; e++) {
      const size_t eoff = ((size_t)n * 8 + e) * 16 + lo;   // x8 elements base
      const float4* wp = (const float4*)(ecw + eoff * 8);
      const float4 w0 = wp[0], w1 = wp[1];
      uint4v pk;
      { f16x2 h = __builtin_amdgcn_cvt_pkrtz(w0.x, w0.y); pk.x = *(uint*)&h; }
      { f16x2 h = __builtin_amdgcn_cvt_pkrtz(w0.z, w0.w); pk.y = *(uint*)&h; }
      { f16x2 h = __builtin_amdgcn_cvt_pkrtz(w1.x, w1.y); pk.z = *(uint*)&h; }
      { f16x2 h = __builtin_amdgcn_cvt_pkrtz(w1.z, w1.w); pk.w = *(uint*)&h; }
      ech4[eoff] = pk;                       // fp16 copy for passes 1-2 (coalesced 16B)
      h8 bv = *(h8*)&pk;
      sacc[e] = __builtin_amdgcn_mfma_f32_16x16x32_f16(a, bv, sacc[e], 0, 0, 0);
    }
  }

  // lane's (e,r) element is slot b*128+e*16+o = (4q+r)*128+e*16+lo
#pragma unroll
  for (int e = 0; e < 8; e++)
#pragma unroll
    for (int r = 0; r < 4; r++)
      red[wv * 2048 + (4 * q + r) * 128 + e * 16 + lo] = sacc[e][r];
  __syncthreads();
#pragma unroll
  for (int m = 0; m < 8; m++) {
    const int slot = t + 256 * m;
    atomicAdd(&sout[slot], red[slot] + red[2048 + slot] + red[4096 + slot] + red[6144 + slot]);
  }
}

template <int PASS>
__global__ __launch_bounds__(256, 4) void route_s1(const float* __restrict__ u, const uint* __restrict__ ech,
                                                   const float* __restrict__ s0g, const float* __restrict__ s1g,
                                                   float* __restrict__ sout) {
  __shared__ float red[4096];    // 16 KB reduce scratch; first 8 KB doubles as us[]
  float* us = red;               // us[wv*512 + bb*64 + nn*8 + i]

  const int t = threadIdx.x, l = t & 63, wv = t >> 6;
  const int b0 = blockIdx.y * 8;
  const int n0 = blockIdx.x * 32 + wv * 8;
  const bool low = l < 32;

  // in-register squash: vv[bb] = v[b0+bb][e=l>>3][o=2(l&7),+1]
  //   PASS 1: v = squash(0.125*s0);  PASS 2: v = squash(0.125*s0) + squash(s1)
  float2 vv[8];
#pragma unroll
  for (int bb = 0; bb < 8; bb++) {
    float2 sp = *(const float2*)&s0g[(size_t)(b0 + bb) * 128 + 2 * l];
    sp.x *= 0.125f; sp.y *= 0.125f;
    float q2 = fmaf(sp.x, sp.x, sp.y * sp.y);
    q2 = dpp_add<0xB1>(q2); q2 = dpp_add<0x4E>(q2); q2 = dpp_add<0x141>(q2);  // sum 16 o
    float f = q2 / (1.f + q2) / (sqrtf(q2) + 1e-8f);
    vv[bb].x = f * sp.x; vv[bb].y = f * sp.y;
    if (PASS == 2) {
      float2 sq = *(const float2*)&s1g[(size_t)(b0 + bb) * 128 + 2 * l];
      float r2 = fmaf(sq.x, sq.x, sq.y * sq.y);
      r2 = dpp_add<0xB1>(r2); r2 = dpp_add<0x4E>(r2); r2 = dpp_add<0x141>(r2);
      float g2 = r2 / (1.f + r2) / (sqrtf(r2) + 1e-8f);
      vv[bb].x = fmaf(g2, sq.x, vv[bb].x); vv[bb].y = fmaf(g2, sq.y, vv[bb].y);
    }
  }

  // stage u slab: 8 b x (8 n x 8 i); wave-private region -> lgkmcnt wait suffices
#pragma unroll
  for (int bb = 0; bb < 8; bb++)
    us[wv * 512 + bb * 64 + l] = u[((size_t)(b0 + bb) * NCAP + n0) * 8 + l];

  float sacc[16];
#pragma unroll
  for (int k = 0; k < 16; k++) sacc[k] = 0.f;

  // lane l holds ec_w[n] halves [16l,16l+16): W[e=l>>3][o0=2(l&7)][i0..7], W[e][o0+1][i0..7]
  const uint4v* hbase = (const uint4v*)(ech + (size_t)n0 * 512) + (l * 2);

  auto proc = [&](int nn, uint4v w0, uint4v w1) {
    float ec[16];
#pragma unroll
    for (int k = 0; k < 4; k++) {
      uint t0 = w0[k], t1 = w1[k];
      f16x2 a = *(f16x2*)&t0;
      f16x2 b = *(f16x2*)&t1;
      ec[2 * k]     = (float)a.x; ec[2 * k + 1] = (float)a.y;
      ec[8 + 2 * k] = (float)b.x; ec[8 + 2 * k + 1] = (float)b.y;
    }
#pragma unroll
    for (int bb = 0; bb < 8; bb++) {
      const float4* up = (const float4*)&us[wv * 512 + bb * 64 + nn * 8];  // same addr all lanes: broadcast
      const float4 ua = up[0], ub = up[1];
      const float uv[8] = {ua.x, ua.y, ua.z, ua.w, ub.x, ub.y, ub.z, ub.w};
      float h0 = 0.f, h1 = 0.f;
#pragma unroll
      for (int k = 0; k < 8; k++) {
        h0 = fmaf(ec[k], uv[k], h0);        // u_hat[b,n,e,o0]
        h1 = fmaf(ec[8 + k], uv[k], h1);    // u_hat[b,n,e,o0+1]
      }
      float p = fmaf(h0, vv[bb].x, h1 * vv[bb].y);
      p = dpp_add<0xB1>(p);    // + lane^1 (quad_perm [1,0,3,2])
      p = dpp_add<0x4E>(p);    // + lane^2 (quad_perm [2,3,0,1])
      p = dpp_add<0x141>(p);   // + lane^4 equiv (row_half_mirror after quad sums)
      const float ex = __expf(p);          // no max-subtract: |b_log| tiny (validated)
      float den = dpp_add<0x140>(ex);      // + lane^8 equiv (row_mirror)
      den += __int_as_float(__builtin_amdgcn_ds_swizzle(__float_as_int(den), 0x401F)); // ^16
      den += xor32_partner(den, low);                                                  // ^32 (VALU)
      const float cc = ex * __builtin_amdgcn_rcpf(den);
      sacc[2 * bb] = fmaf(cc, h0, sacc[2 * bb]);
      sacc[2 * bb + 1] = fmaf(cc, h1, sacc[2 * bb + 1]);
    }
  };

  // nn loop, pinned 2-unrolled with 1-ahead ec register double-buffer (8 regs)
  uint4v ca0 = hbase[0], ca1 = hbase[1];
#pragma unroll 1
  for (int nn = 0; nn < 8; nn += 2) {
    const uint4v* pb = hbase + (size_t)(nn + 1) * 128;
    uint4v cb0 = pb[0], cb1 = pb[1];
    proc(nn, ca0, ca1);
    if (nn + 2 < 8) {
      const uint4v* pa = hbase + (size_t)(nn + 2) * 128;
      ca0 = pa[0]; ca1 = pa[1];
    }
    proc(nn + 1, cb0, cb1);
  }

  // transposed conflict-free block reduce -> one atomic per slot
  __syncthreads();               // all us reads done before clobbering red (alias!)
#pragma unroll
  for (int k = 0; k < 16; k++) red[k * 256 + wv * 64 + l] = sacc[k];
  __syncthreads();
#pragma unroll
  for (int m = 0; m < 4; m++) {
    int slot = t + 256 * m;                       // slot = bl*128 + eo  (bl in [0,8))
    int bl = slot >> 7, eo = slot & 127;
    int k = 2 * bl + (eo & 1), l2 = eo >> 1;
    const float* r = red + k * 256 + l2;
    atomicAdd(&sout[(b0 + bl) * 128 + eo], r[0] + r[64] + r[128] + r[192]);
  }
}

__global__ void squash_out_k(const float* __restrict__ s, float* __restrict__ out) {
  int t = threadIdx.x;   // 128
  float nn = 0.f;
#pragma unroll
  for (int o = 0; o < 16; o++) { float x = s[t * 16 + o]; nn = fmaf(x, x, nn); }
  float norm = sqrtf(nn);
  float f = nn / (1.f + nn) / (norm + 1e-8f);
  out[t] = f * norm;
}

extern "C" void kernel_launch(void* const* d_in, const int* in_sizes, int n_in,
                              void* d_out, int out_size, void* d_ws, size_t ws_size,
                              hipStream_t stream) {
  const float* x   = (const float*)d_in[0];
  const float* w1  = (const float*)d_in[1];
  const float* b1  = (const float*)d_in[2];
  const float* w2  = (const float*)d_in[3];
  const float* b2  = (const float*)d_in[4];
  const float* w3  = (const float*)d_in[5];
  const float* b3  = (const float*)d_in[6];
  const float* pcw = (const float*)d_in[7];
  const float* pcb = (const float*)d_in[8];
  const float* ecw = (const float*)d_in[9];
  float* out = (float*)d_out;

  float* ws = (float*)d_ws;
  size_t o = 0;
  float* hc   = ws + o; o += 3641344;   // conv1 out fp32 NCHW; later aliased as u
  float* yb   = ws + o; o += 3641344;   // conv2 out fp32 NCHW; later aliased as uh
  float* out3 = ws + o; o += 3641344;   // conv3 out
  ushort* hpc = (ushort*)(ws + o); o += 2568192;   // 16*19*264*64 bf16 NHWC padded
  ushort* wb  = (ushort*)(ws + o); o += 73728;     // 64*2304 bf16
  float* w3t  = ws + o; o += 8192;
  float* s0   = ws + o; o += 2048;
  float* s1   = ws + o; o += 2048;
  float* s2   = ws + o; o += 2048;
  float* v0   = ws + o; o += 2048;      // (unused; kept for layout stability)
  float* v1   = ws + o; o += 2048;      // (unused)
  uint* ech   = (uint*)(ws + o); o += 14565376;    // 28448*1024 fp16 = 58.3 MB
  float* ub   = hc;                     // lifetime-disjoint alias (pc_k runs after conv3_k)
  _Float16* uhp = (_Float16*)yb;        // lifetime-disjoint alias (cvt_u runs after conv3_k)
  (void)v0; (void)v1;

  hipMemsetAsync(hpc, 0, (size_t)16 * HPH * HPW2 * 64 * 2, stream);  // zero incl. pad
  hipMemsetAsync(s0, 0, 3 * 2048 * 4, stream);                       // s0|s1|s2 contiguous

  prep_w<<<576, 256, 0, stream>>>(w2, w3, wb, w3t);
  conv1_k<<<dim3(14, 16), 256, 0, stream>>>(x, w1, b1, hc);
  nhwc_k<<<dim3(4, 14, 16), 256, 0, stream>>>(hc, hpc);
  conv2_mfma<<<dim3(2, 14, 16), 256, 0, stream>>>(hpc, wb, b2, yb);
  conv3_k<<<dim3(4, 14, 16), 256, 0, stream>>>(hc, yb, w3t, b3, out3);
  pc_k<<<dim3(112, 2), 256, 0, stream>>>(out3, pcw, pcb, ub);
  cvt_u<<<1778, 256, 0, stream>>>(ub, uhp);        // u -> fp16 [n][b][8]

  // iter 0: fused ec-convert + streaming MFMA GEMM (writes ech for passes 1-2)
  route_cvt0<<<889, 256, 0, stream>>>(uhp, ecw, (uint4v*)ech, s0);
  // iters 1-2: VALU routing with in-kernel squash (v from s0 / s0+s1)
  route_s1<1><<<dim3(889, 2), 256, 0, stream>>>(ub, ech, s0, nullptr, s1);
  route_s1<2><<<dim3(889, 2), 256, 0, stream>>>(ub, ech, s0, s1, s2);
  squash_out_k<<<1, 128, 0, stream>>>(s2, out);
}